// Round 4
// baseline (597.113 us; speedup 1.0000x reference)
//
#include <hip/hip_runtime.h>
#include <hip/hip_fp16.h>

#define BF 256
#define TSTEPS 256

typedef _Float16 h8_t __attribute__((ext_vector_type(8)));
typedef _Float16 h4_t __attribute__((ext_vector_type(4)));
typedef float f4_t __attribute__((ext_vector_type(4)));

union H8 { uint4 u; h8_t v; };
union H4 { uint2 u; h4_t v; };
union U2H4 { uint2 u; __half h[4]; };

// fast sigmoid/tanh: v_exp + v_rcp (error << f16 storage quantization of h)
static __device__ __forceinline__ float sigmoidf_(float x) {
    return __builtin_amdgcn_rcpf(1.f + __expf(-x));
}
static __device__ __forceinline__ float tanhf_(float x) {
    return 1.f - 2.f * __builtin_amdgcn_rcpf(__expf(2.f * x) + 1.f);
}

// LDS-only workgroup barrier: drains lgkmcnt (ds ops) but leaves vmcnt
// (global stores of h / G-prefetch loads) in flight across the barrier.
static __device__ __forceinline__ void wg_barrier_lds() {
    __builtin_amdgcn_sched_barrier(0);
    asm volatile("s_waitcnt lgkmcnt(0)" ::: "memory");
    __builtin_amdgcn_s_barrier();
    __builtin_amdgcn_sched_barrier(0);
}

// ---- pack helper: f16 MFMA operand layout -----------------------------------------
static __device__ __forceinline__ void pack_one(const float* __restrict__ src,
                                                __half* __restrict__ dst,
                                                int OC, int IC, int KS,
                                                int oc_str, int ic_str, int k_str, int i) {
    int grp = KS / 4;
    int j = i % grp;
    int oc = (i / grp) % OC;
    int g = (i / (grp * OC)) & 3;
    int chunk = i / (grp * OC * 4);
    int CPK = IC / KS;
    int cc = chunk % CPK;
    int khw = chunk / CPK;
    int ic = cc * KS + g * grp + j;
    dst[i] = __float2half(src[(long)oc * oc_str + (long)ic * ic_str + khw * k_str]);
}

// Whh pack, 1-seq-per-block variant: packed tile T (16 rows) = 4 classes x 4 units,
// tile row rr = cls*4 + du -> original row cls*128 + unit, where
// unit = (T>>2)*16 + (T&3)*4 + du  (wave w = T>>2 owns units [16w,16w+16)).
static __device__ __forceinline__ void pack_whh_one(const float* __restrict__ src,
                                                    __half* __restrict__ dst, int i) {
    int j = i & 7;
    int prow = (i >> 3) & 511;
    int cg = i >> 12;            // chunk*4 + g
    int g = cg & 3, chunk = cg >> 2;
    int T = prow >> 4, rr = prow & 15;
    int cls = rr >> 2, du = rr & 3;
    int unit = (T >> 2) * 16 + (T & 3) * 4 + du;
    int orig = cls * 128 + unit;
    int ic = chunk * 32 + g * 8 + j;
    dst[i] = __float2half(src[orig * 128 + ic]);
}

// ---- fused weight prep ------------------------------------------------------------
__global__ __launch_bounds__(256) void prep_k(
        const float* __restrict__ w0, const float* __restrict__ w1,
        const float* __restrict__ w2, const float* __restrict__ w3,
        const float* __restrict__ Wihf, const float* __restrict__ Wihb,
        const float* __restrict__ Whhf, const float* __restrict__ Whhb,
        float* __restrict__ w0t, __half* __restrict__ w1p,
        __half* __restrict__ w2p, __half* __restrict__ w3p,
        __half* __restrict__ wfp, __half* __restrict__ wbp,
        __half* __restrict__ whhfp, __half* __restrict__ whhbp) {
    int i = blockIdx.x * 256 + threadIdx.x;
    if (i < 144) { int oc = i / 9, rem = i % 9; w0t[rem * 16 + oc] = w0[i]; return; }
    i -= 144;
    if (i < 4608) { pack_one(w1, w1p, 32, 16, 16, 144, 9, 1, i); return; }
    i -= 4608;
    if (i < 18432) { pack_one(w2, w2p, 64, 32, 32, 288, 9, 1, i); return; }
    i -= 18432;
    if (i < 73728) { pack_one(w3, w3p, 128, 64, 32, 576, 9, 1, i); return; }
    i -= 73728;
    if (i < 65536) { pack_one(Wihf, wfp, 512, 128, 32, 128, 1, 0, i); return; }
    i -= 65536;
    if (i < 65536) { pack_one(Wihb, wbp, 512, 128, 32, 128, 1, 0, i); return; }
    i -= 65536;
    if (i < 65536) { pack_whh_one(Whhf, whhfp, i); return; }
    i -= 65536;
    if (i < 65536) { pack_whh_one(Whhb, whhbp, i); return; }
}

__global__ void pack_wf16(const float* __restrict__ src, __half* __restrict__ dst,
                          int OC, int IC, int KS,
                          int oc_str, int ic_str, int k_str, int total) {
    int i = blockIdx.x * 256 + threadIdx.x;
    if (i >= total) return;
    pack_one(src, dst, OC, IC, KS, oc_str, ic_str, k_str, i);
}

// ---- conv0: 1->16 ch, VALU, NHWC f16 out ------------------------------------------
__global__ __launch_bounds__(256) void conv0_k(const float* __restrict__ in,
                                               const float* __restrict__ wT,
                                               const float* __restrict__ bias,
                                               __half* __restrict__ out) {
    __shared__ float wsm[9][16];
    __shared__ float bs[16];
    int tid = threadIdx.x;
    if (tid < 144) wsm[tid / 16][tid % 16] = wT[tid];
    if (tid < 16) bs[tid] = bias[tid];
    __syncthreads();
    int gid = blockIdx.x * 256 + tid;
    int ow = gid % 27;
    int t = (gid / 27) % 256;
    int bf = gid / (27 * 256);
    float acc[16];
#pragma unroll
    for (int o = 0; o < 16; o++) acc[o] = bs[o];
    int iw0 = ow * 3 - 1;
#pragma unroll
    for (int kh = 0; kh < 3; kh++) {
        int tt = t + kh - 1;
        if ((unsigned)tt >= 256u) continue;
        const float* ip = in + ((long)bf * 256 + tt) * 81;
#pragma unroll
        for (int kw = 0; kw < 3; kw++) {
            int iw = iw0 + kw;
            if ((unsigned)iw >= 81u) continue;
            float x = ip[iw];
#pragma unroll
            for (int o = 0; o < 16; o++) acc[o] += x * wsm[kh * 3 + kw][o];
        }
    }
    __half2* op = (__half2*)(out + (long)gid * 16);
#pragma unroll
    for (int o = 0; o < 8; o++)
        op[o] = __floats2half2_rn(fmaxf(acc[2 * o], 0.f), fmaxf(acc[2 * o + 1], 0.f));
}

// ---- MFMA implicit-GEMM conv: NHWC f16 in/out -------------------------------------
template<int IC, int OC, int WIN, int WOUT, int KS>
__global__ __launch_bounds__(256) void convM_k(const __half* __restrict__ in,
                                               const __half* __restrict__ wp,
                                               const float* __restrict__ bias,
                                               __half* __restrict__ out) {
    constexpr int NT = OC / 16;
    constexpr int CPK = IC / KS;
    constexpr int NCHUNK = 9 * CPK;
    constexpr int GRP = KS / 4;
    int tid = threadIdx.x;
    int lane = tid & 63;
    int wv = tid >> 6;
    int l15 = lane & 15;
    int g = lane >> 4;
    int m = blockIdx.x * 64 + wv * 16 + l15;
    int ow = m % WOUT;
    int t = (m / WOUT) % 256;
    int bf = m / (WOUT * 256);

    f4_t acc[NT];
#pragma unroll
    for (int nt = 0; nt < NT; nt++)
#pragma unroll
        for (int r = 0; r < 4; r++) acc[nt][r] = 0.f;

#pragma unroll
    for (int chunk = 0; chunk < NCHUNK; chunk++) {
        int khw = chunk / CPK, cc = chunk % CPK;
        int kh = khw / 3;
        int kw = khw - kh * 3;
        int tt = t + kh - 1;
        int iw = ow * 3 + kw - 1;
        bool ok = ((unsigned)tt < 256u) && ((unsigned)iw < (unsigned)WIN);
        long aoff = ok ? (((long)(bf * 256 + tt) * WIN + iw) * IC + cc * KS + g * GRP) : 0;
        if constexpr (KS == 32) {
            H8 af;
            af.u = *(const uint4*)(in + aoff);
            if (!ok) af.u = make_uint4(0u, 0u, 0u, 0u);
#pragma unroll
            for (int nt = 0; nt < NT; nt++) {
                H8 bf8;
                bf8.u = *(const uint4*)(wp + ((long)(chunk * 4 + g) * OC + nt * 16 + l15) * GRP);
                acc[nt] = __builtin_amdgcn_mfma_f32_16x16x32_f16(af.v, bf8.v, acc[nt], 0, 0, 0);
            }
        } else {
            H4 af;
            af.u = *(const uint2*)(in + aoff);
            if (!ok) af.u = make_uint2(0u, 0u);
#pragma unroll
            for (int nt = 0; nt < NT; nt++) {
                H4 bf4;
                bf4.u = *(const uint2*)(wp + ((long)(chunk * 4 + g) * OC + nt * 16 + l15) * GRP);
                acc[nt] = __builtin_amdgcn_mfma_f32_16x16x16f16(af.v, bf4.v, acc[nt], 0, 0, 0);
            }
        }
    }
    int orow = blockIdx.x * 64 + wv * 16 + g * 4;
#pragma unroll
    for (int nt = 0; nt < NT; nt++) {
        int oc = nt * 16 + l15;
        float b = bias[oc];
#pragma unroll
        for (int r = 0; r < 4; r++) {
            float v = fmaxf(acc[nt][r] + b, 0.f);
            out[(long)(orow + r) * OC + oc] = __float2half(v);
        }
    }
}

// ---- gates MFMA GEMM, TRANSPOSED output G'[(b*512+gate)*256 + tidx] ---------------
// fwd: tidx = t ; bwd: tidx = 255 - t (so lstm always reads ascending tidx)
__global__ __launch_bounds__(256) void gates_k(const __half* __restrict__ X,
                                               const __half* __restrict__ wpf,
                                               const __half* __restrict__ wpb,
                                               const float* __restrict__ bf1,
                                               const float* __restrict__ bf2,
                                               const float* __restrict__ bb1,
                                               const float* __restrict__ bb2,
                                               __half* __restrict__ Gf,
                                               __half* __restrict__ Gb) {
    int dir = blockIdx.z;
    const __half* wp = dir ? wpb : wpf;
    const float* b1 = dir ? bb1 : bf1;
    const float* b2 = dir ? bb2 : bf2;
    __half* G = dir ? Gb : Gf;
    int tid = threadIdx.x;
    int lane = tid & 63;
    int wv = tid >> 6;
    int l15 = lane & 15;
    int g = lane >> 4;
    long r0 = (long)blockIdx.x * 128 + wv * 32;
    int n0 = blockIdx.y * 128;

    f4_t acc[2][8];
#pragma unroll
    for (int s = 0; s < 2; s++)
#pragma unroll
        for (int nt = 0; nt < 8; nt++)
#pragma unroll
            for (int r = 0; r < 4; r++) acc[s][nt][r] = 0.f;

#pragma unroll
    for (int chunk = 0; chunk < 4; chunk++) {
        H8 a0, a1;
        a0.u = *(const uint4*)(X + (r0 + l15) * 128 + chunk * 32 + g * 8);
        a1.u = *(const uint4*)(X + (r0 + 16 + l15) * 128 + chunk * 32 + g * 8);
#pragma unroll
        for (int nt = 0; nt < 8; nt++) {
            H8 bw;
            bw.u = *(const uint4*)(wp + ((long)(chunk * 4 + g) * 512 + n0 + nt * 16 + l15) * 8);
            acc[0][nt] = __builtin_amdgcn_mfma_f32_16x16x32_f16(a0.v, bw.v, acc[0][nt], 0, 0, 0);
            acc[1][nt] = __builtin_amdgcn_mfma_f32_16x16x32_f16(a1.v, bw.v, acc[1][nt], 0, 0, 0);
        }
    }
    int b = (int)(r0 >> 8);
#pragma unroll
    for (int nt = 0; nt < 8; nt++) {
        int col = n0 + nt * 16 + l15;
        float bias = b1[col] + b2[col];
        long base = ((long)b * 512 + col) * 256;
#pragma unroll
        for (int s = 0; s < 2; s++) {
            int tb = (int)(r0 & 255) + s * 16 + g * 4;
            U2H4 pk;
            if (!dir) {
#pragma unroll
                for (int r = 0; r < 4; r++) pk.h[r] = __float2half(acc[s][nt][r] + bias);
                *(uint2*)(G + base + tb) = pk.u;
            } else {
#pragma unroll
                for (int r = 0; r < 4; r++) pk.h[3 - r] = __float2half(acc[s][nt][r] + bias);
                *(uint2*)(G + base + (252 - tb)) = pk.u;
            }
        }
    }
}

// ---- LSTM recurrence: 512 blocks x 512 thr (8 waves), 1 recurrence per block ------
// 2 blocks/CU -> two INDEPENDENT barrier groups per CU; one group's serial-chain
// stall is hidden by the other group's issue. Wave w owns units [16w,16w+16) x all
// 4 classes (class-interleaved Whh tiles: tile = 4 classes x 4 units, 4 tiles/wave,
// 16 MFMA/step as 4 independent 4-chains). Lane (l15,g2) = class g2 of unit w*16+l15;
// extraction: element (l15&3) of acc[l15>>2]. Cell stitch: 3 shuffles
// (xor32: i<->g f<->o, xor16: f<-i*g, xor32: o<-tanh(c)).
__global__ __launch_bounds__(512, 4) void lstm_k(const __half* __restrict__ Gf,
                                                 const __half* __restrict__ Gb,
                                                 const __half* __restrict__ whhfp,
                                                 const __half* __restrict__ whhbp,
                                                 __half* __restrict__ flat) {
    int bid = blockIdx.x;
    int dir = bid >> 8;
    int seq = bid & 255;
    const __half* G = dir ? Gb : Gf;
    const __half* wp = dir ? whhbp : whhfp;
    int tid = threadIdx.x;
    int w = tid >> 6;            // wave 0..7
    int lane = tid & 63;
    int l15 = lane & 15;
    int g2 = lane >> 4;          // class: 0=i, 1=f, 2=g, 3=o
    int unit = w * 16 + l15;     // 0..127
    int tsel = l15 >> 2;         // which acc tile
    int du = l15 & 3;            // which element

    // A-frags: 4 tiles x 4 k-chunks = 64 VGPRs/lane
    H8 afr[4][4];
#pragma unroll
    for (int t = 0; t < 4; t++) {
        int prow = (w * 4 + t) * 16 + l15;
#pragma unroll
        for (int c = 0; c < 4; c++)
            afr[t][c].u = *(const uint4*)(wp + ((long)((c * 4 + g2) * 512 + prow)) * 8);
    }

    __shared__ __align__(16) __half hbuf[2][128];
    if (tid < 64) ((unsigned int*)hbuf)[tid] = 0u;   // zero hbuf[0][0..127]
    __syncthreads();

    // this lane's single gate row in transposed G
    const __half* gb0 = G + (((long)seq * 512) + g2 * 128 + unit) * 256;

    float cst = 0.f;                         // cell state, valid on g2==1 lanes
    float ma = (g2 == 2) ? 2.f : 1.f;        // tanh(z) = 2*sigmoid(2z)-1 on g-lanes
    float mb = ma;
    float cb = (g2 == 2) ? -1.f : 0.f;
    const f4_t zero4 = {0.f, 0.f, 0.f, 0.f};

    H8 gc, gn;
    gc.u = *(const uint4*)(gb0);
    long fbase = (long)seq * 65536 + dir * 128 + unit;

    for (int to = 0; to < 32; to++) {
        if (to < 31) gn.u = *(const uint4*)(gb0 + (to + 1) * 8);
#pragma unroll
        for (int ti = 0; ti < 8; ti++) {
            int s = to * 8 + ti;
            int p = s & 1;
            H8 bfr[4];
#pragma unroll
            for (int c = 0; c < 4; c++)
                bfr[c].u = *(const uint4*)(&hbuf[p][c * 32 + g2 * 8]);

            f4_t acc[4];
#pragma unroll
            for (int t = 0; t < 4; t++)
                acc[t] = __builtin_amdgcn_mfma_f32_16x16x32_f16(afr[t][0].v, bfr[0].v,
                                                                zero4, 0, 0, 0);
#pragma unroll
            for (int c = 1; c < 4; c++)
#pragma unroll
                for (int t = 0; t < 4; t++)
                    acc[t] = __builtin_amdgcn_mfma_f32_16x16x32_f16(afr[t][c].v, bfr[c].v,
                                                                    acc[t], 0, 0, 0);
            // extract element du of acc[tsel]
            float evt[4];
#pragma unroll
            for (int t = 0; t < 4; t++) {
                float lo = (du & 1) ? acc[t][1] : acc[t][0];
                float hi = (du & 1) ? acc[t][3] : acc[t][2];
                evt[t] = (du & 2) ? hi : lo;
            }
            float e01 = (tsel & 1) ? evt[1] : evt[0];
            float e23 = (tsel & 1) ? evt[3] : evt[2];
            float ev = (tsel & 2) ? e23 : e01;

            float z = ev + (float)gc.v[ti];
            float a = sigmoidf_(ma * z) * mb + cb;   // i,f,o: sigmoid; g: tanh

            float x1 = __shfl_xor(a, 32, 64);        // i<->g, f<->o (same unit)
            float pi = a * x1;                       // on g2=0: sig(i)*tanh(g)
            float x2 = __shfl_xor(pi, 16, 64);       // g2=1 <- g2=0
            float cn = a * cst + x2;                 // on g2=1: sig(f)*c + pi
            cst = cn;
            float tc = tanhf_(cn);
            float x3 = __shfl_xor(tc, 32, 64);       // g2=3 <- g2=1
            float h = a * x3;                        // on g2=3: sig(o)*tanh(c')

            if (g2 == 3) {
                __half hh = __float2half(h);
                int ts = dir ? (255 - s) : s;
                hbuf[p ^ 1][unit] = hh;
                flat[fbase + (long)ts * 256] = hh;
            }
            wg_barrier_lds();
        }
        gc = gn;
    }
}

// ---- FC1 MFMA split-K: z[256][128] += flat16 @ fc1_w16^T --------------------------
__global__ __launch_bounds__(256) void fc1m_k(const __half* __restrict__ flat,
                                              const __half* __restrict__ wp,
                                              float* __restrict__ z) {
    int tid = threadIdx.x;
    int lane = tid & 63;
    int wv = tid >> 6;
    int l15 = lane & 15;
    int g = lane >> 4;
    int m0 = blockIdx.x * 64 + wv * 16;
    long k0 = (long)blockIdx.y * 1024;

    f4_t acc[8];
#pragma unroll
    for (int nt = 0; nt < 8; nt++)
#pragma unroll
        for (int r = 0; r < 4; r++) acc[nt][r] = 0.f;

    for (int c = 0; c < 32; c++) {
        long chunk = (k0 >> 5) + c;
        H8 af;
        af.u = *(const uint4*)(flat + (long)(m0 + l15) * 65536 + k0 + c * 32 + g * 8);
#pragma unroll
        for (int nt = 0; nt < 8; nt++) {
            H8 bw;
            bw.u = *(const uint4*)(wp + ((chunk * 4 + g) * 128 + nt * 16 + l15) * 8);
            acc[nt] = __builtin_amdgcn_mfma_f32_16x16x32_f16(af.v, bw.v, acc[nt], 0, 0, 0);
        }
    }
#pragma unroll
    for (int nt = 0; nt < 8; nt++)
#pragma unroll
        for (int r = 0; r < 4; r++)
            atomicAdd(&z[(m0 + g * 4 + r) * 128 + nt * 16 + l15], acc[nt][r]);
}

__global__ void zero_k(float* __restrict__ p, int n) {
    int i = blockIdx.x * 256 + threadIdx.x;
    if (i < n) p[i] = 0.f;
}

// ---- head -------------------------------------------------------------------------
__global__ __launch_bounds__(256) void head_k(const float* __restrict__ z,
                                              const float* __restrict__ b1,
                                              const float* __restrict__ fsw,
                                              const float* __restrict__ fsb,
                                              float* __restrict__ out) {
    __shared__ float sf[256];
    int r = threadIdx.x;
    float acc = fsb[0];
#pragma unroll
    for (int j4 = 0; j4 < 32; j4++) {
        float4 zv = *(const float4*)&z[r * 128 + j4 * 4];
        float4 bv = *(const float4*)&b1[j4 * 4];
        float4 wv = *(const float4*)&fsw[j4 * 4];
        acc += fmaxf(zv.x + bv.x, 0.f) * wv.x;
        acc += fmaxf(zv.y + bv.y, 0.f) * wv.y;
        acc += fmaxf(zv.z + bv.z, 0.f) * wv.z;
        acc += fmaxf(zv.w + bv.w, 0.f) * wv.w;
    }
    float val = sigmoidf_(acc) * 4.f + 1.f;
    out[16 + r] = val;
    sf[r] = val;
    __syncthreads();
    if (r < 16) {
        float m = 0.f;
#pragma unroll
        for (int f = 0; f < 16; f++) m += sf[r * 16 + f];
        out[r] = m * (1.f / 16.f);
    }
}

extern "C" void kernel_launch(void* const* d_in, const int* in_sizes, int n_in,
                              void* d_out, int out_size, void* d_ws, size_t ws_size,
                              hipStream_t stream) {
    const float* audio = (const float*)d_in[0];
    const float* w0 = (const float*)d_in[2];
    const float* b0 = (const float*)d_in[3];
    const float* w1 = (const float*)d_in[4];
    const float* b1 = (const float*)d_in[5];
    const float* w2 = (const float*)d_in[6];
    const float* b2 = (const float*)d_in[7];
    const float* w3 = (const float*)d_in[8];
    const float* b3 = (const float*)d_in[9];
    const float* Wih_f = (const float*)d_in[10];
    const float* Whh_f = (const float*)d_in[11];
    const float* bih_f = (const float*)d_in[12];
    const float* bhh_f = (const float*)d_in[13];
    const float* Wih_b = (const float*)d_in[14];
    const float* Whh_b = (const float*)d_in[15];
    const float* bih_b = (const float*)d_in[16];
    const float* bhh_b = (const float*)d_in[17];
    const float* fc1_w = (const float*)d_in[18];
    const float* fc1_b = (const float*)d_in[19];
    const float* fs_w = (const float*)d_in[20];
    const float* fs_b = (const float*)d_in[21];
    float* out = (float*)d_out;

    char* ws = (char*)d_ws;
    // lifetimes: out1 dies before Gf; out0 dies before flat16; Gf/Gb die before fc1p
    __half* Gf    = (__half*)(ws);                    // 67.1 MB (transposed layout)
    __half* out1  = (__half*)(ws);                    // 37.7 MB (pre-Gf)
    __half* fc1p  = (__half*)(ws);                    // 16.8 MB (post-lstm, in Gf)
    __half* Gb    = (__half*)(ws + 67108864);         // 67.1 MB
    __half* flat16= (__half*)(ws + 134217728);        // 33.6 MB
    __half* out0  = (__half*)(ws + 134217728);        // 56.6 MB (pre-flat16)
    __half* X     = (__half*)(ws + 201326592);        // 16.8 MB
    __half* out2  = (__half*)(ws + 218103808);        // 25.2 MB
    char* rd = ws + 243269632;
    float*  w0t   = (float*)(rd);
    __half* w1p   = (__half*)(rd + 1024);
    __half* w2p   = (__half*)(rd + 10240);
    __half* w3p   = (__half*)(rd + 47104);
    __half* wfp   = (__half*)(rd + 194560);
    __half* wbp   = (__half*)(rd + 325632);
    __half* whhfp = (__half*)(rd + 456704);
    __half* whhbp = (__half*)(rd + 587776);
    float*  zbuf  = (float*)(rd + 718848);

    // fused weight prep (1 launch)
    prep_k<<<1403, 256, 0, stream>>>(w0, w1, w2, w3, Wih_f, Wih_b, Whh_f, Whh_b,
                                     w0t, w1p, w2p, w3p, wfp, wbp, whhfp, whhbp);

    // conv chain (NHWC f16)
    conv0_k<<<6912, 256, 0, stream>>>(audio, w0t, b0, out0);
    convM_k<16, 32, 27, 9, 16><<<9216, 256, 0, stream>>>(out0, w1p, b1, out1);
    convM_k<32, 64, 9, 3, 32><<<3072, 256, 0, stream>>>(out1, w2p, b2, out2);
    convM_k<64, 128, 3, 1, 32><<<1024, 256, 0, stream>>>(out2, w3p, b3, X);

    // gates, both directions, transposed G output
    gates_k<<<dim3(512, 4, 2), 256, 0, stream>>>(X, wfp, wbp, bih_f, bhh_f,
                                                 bih_b, bhh_b, Gf, Gb);

    // recurrence: 512 blocks (1 per seq,dir), 2 blocks/CU for chain overlap
    lstm_k<<<512, 512, 0, stream>>>(Gf, Gb, whhfp, whhbp, flat16);

    // FC head: pack fc1_w (into dead Gf region), split-K MFMA, head
    pack_wf16<<<32768, 256, 0, stream>>>(fc1_w, fc1p, 128, 65536, 32, 65536, 1, 0, 8388608);
    zero_k<<<128, 256, 0, stream>>>(zbuf, 256 * 128);
    fc1m_k<<<dim3(4, 64), 256, 0, stream>>>(flat16, fc1p, zbuf);
    head_k<<<1, 256, 0, stream>>>(zbuf, fc1_b, fs_w, fs_b, out);
}

// Round 5
// 534.818 us; speedup vs baseline: 1.1165x; 1.1165x over previous
//
#include <hip/hip_runtime.h>
#include <hip/hip_fp16.h>

#define BF 256
#define TSTEPS 256

typedef _Float16 h8_t __attribute__((ext_vector_type(8)));
typedef _Float16 h4_t __attribute__((ext_vector_type(4)));
typedef float f4_t __attribute__((ext_vector_type(4)));

union H8 { uint4 u; h8_t v; };
union H4 { uint2 u; h4_t v; };
union U2H4 { uint2 u; __half h[4]; };

// fast sigmoid/tanh: v_exp + v_rcp (error << f16 storage quantization of h)
static __device__ __forceinline__ float sigmoidf_(float x) {
    return __builtin_amdgcn_rcpf(1.f + __expf(-x));
}
static __device__ __forceinline__ float tanhf_(float x) {
    return 1.f - 2.f * __builtin_amdgcn_rcpf(__expf(2.f * x) + 1.f);
}

// xor-32 lane exchange on the VALU (v_permlane32_swap_b32) instead of the LDS
// crossbar (ds_swizzle): takes the op off the saturated LDS pipe and cuts its
// dependent latency from ~150cy (loaded ds) to ~4cy. Bit-exact vs __shfl_xor(x,32).
// permlane32_swap(D=x,S=x): r0 = new D = [x.lo | x.lo], r1 = new S = [x.hi | x.hi];
// lane<32 wants x[lane+32] -> r1; lane>=32 wants x[lane-32] -> r0.
static __device__ __forceinline__ float xswap32(float x, int lane) {
    typedef unsigned uv2 __attribute__((ext_vector_type(2)));
    unsigned xu = __float_as_uint(x);
    uv2 r = __builtin_amdgcn_permlane32_swap(xu, xu, false, false);
    return __uint_as_float((lane & 32) ? r[0] : r[1]);
}

// LDS-only workgroup barrier: drains lgkmcnt (ds ops) but leaves vmcnt
// (global stores of h / G-prefetch loads) in flight across the barrier.
static __device__ __forceinline__ void wg_barrier_lds() {
    __builtin_amdgcn_sched_barrier(0);
    asm volatile("s_waitcnt lgkmcnt(0)" ::: "memory");
    __builtin_amdgcn_s_barrier();
    __builtin_amdgcn_sched_barrier(0);
}

// ---- pack helper: f16 MFMA operand layout -----------------------------------------
static __device__ __forceinline__ void pack_one(const float* __restrict__ src,
                                                __half* __restrict__ dst,
                                                int OC, int IC, int KS,
                                                int oc_str, int ic_str, int k_str, int i) {
    int grp = KS / 4;
    int j = i % grp;
    int oc = (i / grp) % OC;
    int g = (i / (grp * OC)) & 3;
    int chunk = i / (grp * OC * 4);
    int CPK = IC / KS;
    int cc = chunk % CPK;
    int khw = chunk / CPK;
    int ic = cc * KS + g * grp + j;
    dst[i] = __float2half(src[(long)oc * oc_str + (long)ic * ic_str + khw * k_str]);
}

// Whh pack with class-interleaved row permutation: packed row prow = t*16 + cls*4 + du
// maps to original row cls*128 + t*4 + du. A 16-row MFMA tile then holds
// 4 classes x 4 units, so one wave (2 tiles) covers 8 units x all 4 classes.
static __device__ __forceinline__ void pack_whh_one(const float* __restrict__ src,
                                                    __half* __restrict__ dst, int i) {
    int j = i & 7;
    int prow = (i >> 3) & 511;
    int cg = i >> 12;            // chunk*4 + g
    int g = cg & 3, chunk = cg >> 2;
    int t = prow >> 4, rr = prow & 15;
    int cls = rr >> 2, du = rr & 3;
    int orig = cls * 128 + t * 4 + du;
    int ic = chunk * 32 + g * 8 + j;
    dst[i] = __float2half(src[orig * 128 + ic]);
}

// ---- fused weight prep ------------------------------------------------------------
__global__ __launch_bounds__(256) void prep_k(
        const float* __restrict__ w0, const float* __restrict__ w1,
        const float* __restrict__ w2, const float* __restrict__ w3,
        const float* __restrict__ Wihf, const float* __restrict__ Wihb,
        const float* __restrict__ Whhf, const float* __restrict__ Whhb,
        float* __restrict__ w0t, __half* __restrict__ w1p,
        __half* __restrict__ w2p, __half* __restrict__ w3p,
        __half* __restrict__ wfp, __half* __restrict__ wbp,
        __half* __restrict__ whhfp, __half* __restrict__ whhbp) {
    int i = blockIdx.x * 256 + threadIdx.x;
    if (i < 144) { int oc = i / 9, rem = i % 9; w0t[rem * 16 + oc] = w0[i]; return; }
    i -= 144;
    if (i < 4608) { pack_one(w1, w1p, 32, 16, 16, 144, 9, 1, i); return; }
    i -= 4608;
    if (i < 18432) { pack_one(w2, w2p, 64, 32, 32, 288, 9, 1, i); return; }
    i -= 18432;
    if (i < 73728) { pack_one(w3, w3p, 128, 64, 32, 576, 9, 1, i); return; }
    i -= 73728;
    if (i < 65536) { pack_one(Wihf, wfp, 512, 128, 32, 128, 1, 0, i); return; }
    i -= 65536;
    if (i < 65536) { pack_one(Wihb, wbp, 512, 128, 32, 128, 1, 0, i); return; }
    i -= 65536;
    if (i < 65536) { pack_whh_one(Whhf, whhfp, i); return; }
    i -= 65536;
    if (i < 65536) { pack_whh_one(Whhb, whhbp, i); return; }
}

__global__ void pack_wf16(const float* __restrict__ src, __half* __restrict__ dst,
                          int OC, int IC, int KS,
                          int oc_str, int ic_str, int k_str, int total) {
    int i = blockIdx.x * 256 + threadIdx.x;
    if (i >= total) return;
    pack_one(src, dst, OC, IC, KS, oc_str, ic_str, k_str, i);
}

// ---- conv0: 1->16 ch, VALU, NHWC f16 out ------------------------------------------
__global__ __launch_bounds__(256) void conv0_k(const float* __restrict__ in,
                                               const float* __restrict__ wT,
                                               const float* __restrict__ bias,
                                               __half* __restrict__ out) {
    __shared__ float wsm[9][16];
    __shared__ float bs[16];
    int tid = threadIdx.x;
    if (tid < 144) wsm[tid / 16][tid % 16] = wT[tid];
    if (tid < 16) bs[tid] = bias[tid];
    __syncthreads();
    int gid = blockIdx.x * 256 + tid;
    int ow = gid % 27;
    int t = (gid / 27) % 256;
    int bf = gid / (27 * 256);
    float acc[16];
#pragma unroll
    for (int o = 0; o < 16; o++) acc[o] = bs[o];
    int iw0 = ow * 3 - 1;
#pragma unroll
    for (int kh = 0; kh < 3; kh++) {
        int tt = t + kh - 1;
        if ((unsigned)tt >= 256u) continue;
        const float* ip = in + ((long)bf * 256 + tt) * 81;
#pragma unroll
        for (int kw = 0; kw < 3; kw++) {
            int iw = iw0 + kw;
            if ((unsigned)iw >= 81u) continue;
            float x = ip[iw];
#pragma unroll
            for (int o = 0; o < 16; o++) acc[o] += x * wsm[kh * 3 + kw][o];
        }
    }
    __half2* op = (__half2*)(out + (long)gid * 16);
#pragma unroll
    for (int o = 0; o < 8; o++)
        op[o] = __floats2half2_rn(fmaxf(acc[2 * o], 0.f), fmaxf(acc[2 * o + 1], 0.f));
}

// ---- MFMA implicit-GEMM conv: NHWC f16 in/out -------------------------------------
template<int IC, int OC, int WIN, int WOUT, int KS>
__global__ __launch_bounds__(256) void convM_k(const __half* __restrict__ in,
                                               const __half* __restrict__ wp,
                                               const float* __restrict__ bias,
                                               __half* __restrict__ out) {
    constexpr int NT = OC / 16;
    constexpr int CPK = IC / KS;
    constexpr int NCHUNK = 9 * CPK;
    constexpr int GRP = KS / 4;
    int tid = threadIdx.x;
    int lane = tid & 63;
    int wv = tid >> 6;
    int l15 = lane & 15;
    int g = lane >> 4;
    int m = blockIdx.x * 64 + wv * 16 + l15;
    int ow = m % WOUT;
    int t = (m / WOUT) % 256;
    int bf = m / (WOUT * 256);

    f4_t acc[NT];
#pragma unroll
    for (int nt = 0; nt < NT; nt++)
#pragma unroll
        for (int r = 0; r < 4; r++) acc[nt][r] = 0.f;

#pragma unroll
    for (int chunk = 0; chunk < NCHUNK; chunk++) {
        int khw = chunk / CPK, cc = chunk % CPK;
        int kh = khw / 3;
        int kw = khw - kh * 3;
        int tt = t + kh - 1;
        int iw = ow * 3 + kw - 1;
        bool ok = ((unsigned)tt < 256u) && ((unsigned)iw < (unsigned)WIN);
        long aoff = ok ? (((long)(bf * 256 + tt) * WIN + iw) * IC + cc * KS + g * GRP) : 0;
        if constexpr (KS == 32) {
            H8 af;
            af.u = *(const uint4*)(in + aoff);
            if (!ok) af.u = make_uint4(0u, 0u, 0u, 0u);
#pragma unroll
            for (int nt = 0; nt < NT; nt++) {
                H8 bf8;
                bf8.u = *(const uint4*)(wp + ((long)(chunk * 4 + g) * OC + nt * 16 + l15) * GRP);
                acc[nt] = __builtin_amdgcn_mfma_f32_16x16x32_f16(af.v, bf8.v, acc[nt], 0, 0, 0);
            }
        } else {
            H4 af;
            af.u = *(const uint2*)(in + aoff);
            if (!ok) af.u = make_uint2(0u, 0u);
#pragma unroll
            for (int nt = 0; nt < NT; nt++) {
                H4 bf4;
                bf4.u = *(const uint2*)(wp + ((long)(chunk * 4 + g) * OC + nt * 16 + l15) * GRP);
                acc[nt] = __builtin_amdgcn_mfma_f32_16x16x16f16(af.v, bf4.v, acc[nt], 0, 0, 0);
            }
        }
    }
    int orow = blockIdx.x * 64 + wv * 16 + g * 4;
#pragma unroll
    for (int nt = 0; nt < NT; nt++) {
        int oc = nt * 16 + l15;
        float b = bias[oc];
#pragma unroll
        for (int r = 0; r < 4; r++) {
            float v = fmaxf(acc[nt][r] + b, 0.f);
            out[(long)(orow + r) * OC + oc] = __float2half(v);
        }
    }
}

// ---- gates MFMA GEMM, TRANSPOSED output G'[(b*512+gate)*256 + tidx] ---------------
// fwd: tidx = t ; bwd: tidx = 255 - t (so lstm always reads ascending tidx)
__global__ __launch_bounds__(256) void gates_k(const __half* __restrict__ X,
                                               const __half* __restrict__ wpf,
                                               const __half* __restrict__ wpb,
                                               const float* __restrict__ bf1,
                                               const float* __restrict__ bf2,
                                               const float* __restrict__ bb1,
                                               const float* __restrict__ bb2,
                                               __half* __restrict__ Gf,
                                               __half* __restrict__ Gb) {
    int dir = blockIdx.z;
    const __half* wp = dir ? wpb : wpf;
    const float* b1 = dir ? bb1 : bf1;
    const float* b2 = dir ? bb2 : bf2;
    __half* G = dir ? Gb : Gf;
    int tid = threadIdx.x;
    int lane = tid & 63;
    int wv = tid >> 6;
    int l15 = lane & 15;
    int g = lane >> 4;
    long r0 = (long)blockIdx.x * 128 + wv * 32;
    int n0 = blockIdx.y * 128;

    f4_t acc[2][8];
#pragma unroll
    for (int s = 0; s < 2; s++)
#pragma unroll
        for (int nt = 0; nt < 8; nt++)
#pragma unroll
            for (int r = 0; r < 4; r++) acc[s][nt][r] = 0.f;

#pragma unroll
    for (int chunk = 0; chunk < 4; chunk++) {
        H8 a0, a1;
        a0.u = *(const uint4*)(X + (r0 + l15) * 128 + chunk * 32 + g * 8);
        a1.u = *(const uint4*)(X + (r0 + 16 + l15) * 128 + chunk * 32 + g * 8);
#pragma unroll
        for (int nt = 0; nt < 8; nt++) {
            H8 bw;
            bw.u = *(const uint4*)(wp + ((long)(chunk * 4 + g) * 512 + n0 + nt * 16 + l15) * 8);
            acc[0][nt] = __builtin_amdgcn_mfma_f32_16x16x32_f16(a0.v, bw.v, acc[0][nt], 0, 0, 0);
            acc[1][nt] = __builtin_amdgcn_mfma_f32_16x16x32_f16(a1.v, bw.v, acc[1][nt], 0, 0, 0);
        }
    }
    int b = (int)(r0 >> 8);
#pragma unroll
    for (int nt = 0; nt < 8; nt++) {
        int col = n0 + nt * 16 + l15;
        float bias = b1[col] + b2[col];
        long base = ((long)b * 512 + col) * 256;
#pragma unroll
        for (int s = 0; s < 2; s++) {
            int tb = (int)(r0 & 255) + s * 16 + g * 4;
            U2H4 pk;
            if (!dir) {
#pragma unroll
                for (int r = 0; r < 4; r++) pk.h[r] = __float2half(acc[s][nt][r] + bias);
                *(uint2*)(G + base + tb) = pk.u;
            } else {
#pragma unroll
                for (int r = 0; r < 4; r++) pk.h[3 - r] = __float2half(acc[s][nt][r] + bias);
                *(uint2*)(G + base + (252 - tb)) = pk.u;
            }
        }
    }
}

// ---- LSTM recurrence: 256 blocks x 1024 thr (16 waves), 1 gate value per lane -----
// Whh is packed class-interleaved: tile (16 rows) = 4 classes x 4 units, wave w owns
// tiles {2w,2w+1} = units [8w,8w+8) x classes {i,f,g,o}. MFMA cols duplicate the 2
// seqs 8x, so lane (l15,g2) holds class g2, units du 0..3 (x2 tiles), seq l15>>3.
// Each lane processes ONE gate value; cell update stitched with 3 exchanges:
// xor32 (permlane32_swap, VALU): i<->g f<->o; xor16 (shfl): f<-i*g;
// xor32 (permlane32_swap): o<-tanh(c). Two of three are off the LDS pipe.
__global__ __launch_bounds__(1024, 4) void lstm_k(const __half* __restrict__ Gf,
                                                  const __half* __restrict__ Gb,
                                                  const __half* __restrict__ whhfp,
                                                  const __half* __restrict__ whhbp,
                                                  __half* __restrict__ flat) {
    int bid = blockIdx.x;
    int dir = bid >> 7;
    int b0 = (bid & 127) * 2;
    const __half* G = dir ? Gb : Gf;
    const __half* wp = dir ? whhbp : whhfp;
    int tid = threadIdx.x;
    int w = tid >> 6;            // wave 0..15
    int lane = tid & 63;
    int l15 = lane & 15;
    int g2 = lane >> 4;          // class: 0=i, 1=f, 2=g, 3=o
    int chn = l15 >> 3;          // seq within block
    int u8 = l15 & 7;            // unit within wave's 8
    int unit = w * 8 + u8;       // 0..127
    int tsel = (u8 >> 2) & 1;
    int du = u8 & 3;

    // A-frags: 2 tiles x 4 k-chunks = 32 VGPRs/lane
    H8 afr[2][4];
#pragma unroll
    for (int t = 0; t < 2; t++) {
        int prow = (w * 2 + t) * 16 + l15;
#pragma unroll
        for (int c = 0; c < 4; c++)
            afr[t][c].u = *(const uint4*)(wp + ((long)((c * 4 + g2) * 512 + prow)) * 8);
    }

    __shared__ __align__(16) __half hbuf[2][2][128];
    if (tid < 256) hbuf[0][tid >> 7][tid & 127] = __float2half(0.f);
    __syncthreads();

    // this lane's single gate row in transposed G
    const __half* gb0 = G + (((long)(b0 + chn) * 512) + g2 * 128 + unit) * 256;

    float cst = 0.f;                         // cell state, valid on g2==1 lanes
    float ma = (g2 == 2) ? 2.f : 1.f;        // tanh(z) = 2*sigmoid(2z)-1 on g-lanes
    float mb = ma;
    float cb = (g2 == 2) ? -1.f : 0.f;
    const f4_t zero4 = {0.f, 0.f, 0.f, 0.f};

    H8 gc, gn;
    gc.u = *(const uint4*)(gb0);
    long fbase = (long)(b0 + chn) * 65536 + dir * 128 + unit;

    for (int to = 0; to < 32; to++) {
        if (to < 31) gn.u = *(const uint4*)(gb0 + (to + 1) * 8);
#pragma unroll
        for (int ti = 0; ti < 8; ti++) {
            int s = to * 8 + ti;
            int p = s & 1;
            H8 bfr[4];
#pragma unroll
            for (int c = 0; c < 4; c++)
                bfr[c].u = *(const uint4*)(&hbuf[p][chn][c * 32 + g2 * 8]);

            f4_t acc[2];
#pragma unroll
            for (int t = 0; t < 2; t++)
                acc[t] = __builtin_amdgcn_mfma_f32_16x16x32_f16(afr[t][0].v, bfr[0].v,
                                                                zero4, 0, 0, 0);
#pragma unroll
            for (int c = 1; c < 4; c++)
#pragma unroll
                for (int t = 0; t < 2; t++)
                    acc[t] = __builtin_amdgcn_mfma_f32_16x16x32_f16(afr[t][c].v, bfr[c].v,
                                                                    acc[t], 0, 0, 0);
            // select acc[tsel][du]
            f4_t at;
#pragma unroll
            for (int e = 0; e < 4; e++) at[e] = tsel ? acc[1][e] : acc[0][e];
            float lo = (du & 1) ? at[1] : at[0];
            float hi = (du & 1) ? at[3] : at[2];
            float ev = (du & 2) ? hi : lo;

            float z = ev + (float)gc.v[ti];
            float a = sigmoidf_(ma * z) * mb + cb;   // i,f,o: sigmoid; g: tanh

            float x1 = xswap32(a, lane);             // i<->g, f<->o (VALU permlane)
            float pi = a * x1;                       // on g2=0: sig(i)*tanh(g)
            float x2 = __shfl_xor(pi, 16, 64);       // g2=1 <- g2=0
            float cn = a * cst + x2;                 // on g2=1: sig(f)*c + pi
            cst = cn;
            float tc = tanhf_(cn);
            float x3 = xswap32(tc, lane);            // g2=3 <- g2=1 (VALU permlane)
            float h = a * x3;                        // on g2=3: sig(o)*tanh(c')

            if (g2 == 3) {
                __half hh = __float2half(h);
                int ts = dir ? (255 - s) : s;
                hbuf[p ^ 1][chn][unit] = hh;
                flat[fbase + (long)ts * 256] = hh;
            }
            wg_barrier_lds();
        }
        gc = gn;
    }
}

// ---- FC1 MFMA split-K: z[256][128] += flat16 @ fc1_w16^T --------------------------
__global__ __launch_bounds__(256) void fc1m_k(const __half* __restrict__ flat,
                                              const __half* __restrict__ wp,
                                              float* __restrict__ z) {
    int tid = threadIdx.x;
    int lane = tid & 63;
    int wv = tid >> 6;
    int l15 = lane & 15;
    int g = lane >> 4;
    int m0 = blockIdx.x * 64 + wv * 16;
    long k0 = (long)blockIdx.y * 1024;

    f4_t acc[8];
#pragma unroll
    for (int nt = 0; nt < 8; nt++)
#pragma unroll
        for (int r = 0; r < 4; r++) acc[nt][r] = 0.f;

    for (int c = 0; c < 32; c++) {
        long chunk = (k0 >> 5) + c;
        H8 af;
        af.u = *(const uint4*)(flat + (long)(m0 + l15) * 65536 + k0 + c * 32 + g * 8);
#pragma unroll
        for (int nt = 0; nt < 8; nt++) {
            H8 bw;
            bw.u = *(const uint4*)(wp + ((chunk * 4 + g) * 128 + nt * 16 + l15) * 8);
            acc[nt] = __builtin_amdgcn_mfma_f32_16x16x32_f16(af.v, bw.v, acc[nt], 0, 0, 0);
        }
    }
#pragma unroll
    for (int nt = 0; nt < 8; nt++)
#pragma unroll
        for (int r = 0; r < 4; r++)
            atomicAdd(&z[(m0 + g * 4 + r) * 128 + nt * 16 + l15], acc[nt][r]);
}

__global__ void zero_k(float* __restrict__ p, int n) {
    int i = blockIdx.x * 256 + threadIdx.x;
    if (i < n) p[i] = 0.f;
}

// ---- head -------------------------------------------------------------------------
__global__ __launch_bounds__(256) void head_k(const float* __restrict__ z,
                                              const float* __restrict__ b1,
                                              const float* __restrict__ fsw,
                                              const float* __restrict__ fsb,
                                              float* __restrict__ out) {
    __shared__ float sf[256];
    int r = threadIdx.x;
    float acc = fsb[0];
#pragma unroll
    for (int j4 = 0; j4 < 32; j4++) {
        float4 zv = *(const float4*)&z[r * 128 + j4 * 4];
        float4 bv = *(const float4*)&b1[j4 * 4];
        float4 wv = *(const float4*)&fsw[j4 * 4];
        acc += fmaxf(zv.x + bv.x, 0.f) * wv.x;
        acc += fmaxf(zv.y + bv.y, 0.f) * wv.y;
        acc += fmaxf(zv.z + bv.z, 0.f) * wv.z;
        acc += fmaxf(zv.w + bv.w, 0.f) * wv.w;
    }
    float val = sigmoidf_(acc) * 4.f + 1.f;
    out[16 + r] = val;
    sf[r] = val;
    __syncthreads();
    if (r < 16) {
        float m = 0.f;
#pragma unroll
        for (int f = 0; f < 16; f++) m += sf[r * 16 + f];
        out[r] = m * (1.f / 16.f);
    }
}

extern "C" void kernel_launch(void* const* d_in, const int* in_sizes, int n_in,
                              void* d_out, int out_size, void* d_ws, size_t ws_size,
                              hipStream_t stream) {
    const float* audio = (const float*)d_in[0];
    const float* w0 = (const float*)d_in[2];
    const float* b0 = (const float*)d_in[3];
    const float* w1 = (const float*)d_in[4];
    const float* b1 = (const float*)d_in[5];
    const float* w2 = (const float*)d_in[6];
    const float* b2 = (const float*)d_in[7];
    const float* w3 = (const float*)d_in[8];
    const float* b3 = (const float*)d_in[9];
    const float* Wih_f = (const float*)d_in[10];
    const float* Whh_f = (const float*)d_in[11];
    const float* bih_f = (const float*)d_in[12];
    const float* bhh_f = (const float*)d_in[13];
    const float* Wih_b = (const float*)d_in[14];
    const float* Whh_b = (const float*)d_in[15];
    const float* bih_b = (const float*)d_in[16];
    const float* bhh_b = (const float*)d_in[17];
    const float* fc1_w = (const float*)d_in[18];
    const float* fc1_b = (const float*)d_in[19];
    const float* fs_w = (const float*)d_in[20];
    const float* fs_b = (const float*)d_in[21];
    float* out = (float*)d_out;

    char* ws = (char*)d_ws;
    // lifetimes: out1 dies before Gf; out0 dies before flat16; Gf/Gb die before fc1p
    __half* Gf    = (__half*)(ws);                    // 67.1 MB (transposed layout)
    __half* out1  = (__half*)(ws);                    // 37.7 MB (pre-Gf)
    __half* fc1p  = (__half*)(ws);                    // 16.8 MB (post-lstm, in Gf)
    __half* Gb    = (__half*)(ws + 67108864);         // 67.1 MB
    __half* flat16= (__half*)(ws + 134217728);        // 33.6 MB
    __half* out0  = (__half*)(ws + 134217728);        // 56.6 MB (pre-flat16)
    __half* X     = (__half*)(ws + 201326592);        // 16.8 MB
    __half* out2  = (__half*)(ws + 218103808);        // 25.2 MB
    char* rd = ws + 243269632;
    float*  w0t   = (float*)(rd);
    __half* w1p   = (__half*)(rd + 1024);
    __half* w2p   = (__half*)(rd + 10240);
    __half* w3p   = (__half*)(rd + 47104);
    __half* wfp   = (__half*)(rd + 194560);
    __half* wbp   = (__half*)(rd + 325632);
    __half* whhfp = (__half*)(rd + 456704);
    __half* whhbp = (__half*)(rd + 587776);
    float*  zbuf  = (float*)(rd + 718848);

    // fused weight prep (1 launch)
    prep_k<<<1403, 256, 0, stream>>>(w0, w1, w2, w3, Wih_f, Wih_b, Whh_f, Whh_b,
                                     w0t, w1p, w2p, w3p, wfp, wbp, whhfp, whhbp);

    // conv chain (NHWC f16)
    conv0_k<<<6912, 256, 0, stream>>>(audio, w0t, b0, out0);
    convM_k<16, 32, 27, 9, 16><<<9216, 256, 0, stream>>>(out0, w1p, b1, out1);
    convM_k<32, 64, 9, 3, 32><<<3072, 256, 0, stream>>>(out1, w2p, b2, out2);
    convM_k<64, 128, 3, 1, 32><<<1024, 256, 0, stream>>>(out2, w3p, b3, X);

    // gates, both directions, transposed G output
    gates_k<<<dim3(512, 4, 2), 256, 0, stream>>>(X, wfp, wbp, bih_f, bhh_f,
                                                 bih_b, bhh_b, Gf, Gb);

    // recurrence (16 waves, 1 gate value/lane, permlane stitches, 1 lgkm barrier/step)
    lstm_k<<<256, 1024, 0, stream>>>(Gf, Gb, whhfp, whhbp, flat16);

    // FC head: pack fc1_w (into dead Gf region), split-K MFMA, head
    pack_wf16<<<32768, 256, 0, stream>>>(fc1_w, fc1p, 128, 65536, 32, 65536, 1, 0, 8388608);
    zero_k<<<128, 256, 0, stream>>>(zbuf, 256 * 128);
    fc1m_k<<<dim3(4, 64), 256, 0, stream>>>(flat16, fc1p, zbuf);
    head_k<<<1, 256, 0, stream>>>(zbuf, fc1_b, fs_w, fs_b, out);
}

// Round 6
// 522.261 us; speedup vs baseline: 1.1433x; 1.0240x over previous
//
#include <hip/hip_runtime.h>
#include <hip/hip_fp16.h>

#define BF 256
#define TSTEPS 256

typedef _Float16 h8_t __attribute__((ext_vector_type(8)));
typedef _Float16 h4_t __attribute__((ext_vector_type(4)));
typedef float f4_t __attribute__((ext_vector_type(4)));

union H8 { uint4 u; h8_t v; };
union H4 { uint2 u; h4_t v; };
union U2H4 { uint2 u; __half h[4]; };

// fast sigmoid/tanh: v_exp + v_rcp (error << f16 storage quantization of h)
static __device__ __forceinline__ float sigmoidf_(float x) {
    return __builtin_amdgcn_rcpf(1.f + __expf(-x));
}
static __device__ __forceinline__ float tanhf_(float x) {
    return 1.f - 2.f * __builtin_amdgcn_rcpf(__expf(2.f * x) + 1.f);
}

// xor-32 lane exchange on the VALU (v_permlane32_swap_b32) instead of the LDS
// crossbar (ds_swizzle). Bit-exact vs __shfl_xor(x,32).
static __device__ __forceinline__ float xswap32(float x, int lane) {
    typedef unsigned uv2 __attribute__((ext_vector_type(2)));
    unsigned xu = __float_as_uint(x);
    uv2 r = __builtin_amdgcn_permlane32_swap(xu, xu, false, false);
    return __uint_as_float((lane & 32) ? r[0] : r[1]);
}

// LDS-only workgroup barrier: drains lgkmcnt (ds ops) but leaves vmcnt
// (global stores of h / G-prefetch loads) in flight across the barrier.
static __device__ __forceinline__ void wg_barrier_lds() {
    __builtin_amdgcn_sched_barrier(0);
    asm volatile("s_waitcnt lgkmcnt(0)" ::: "memory");
    __builtin_amdgcn_s_barrier();
    __builtin_amdgcn_sched_barrier(0);
}

// ---- pack helper: f16 MFMA operand layout -----------------------------------------
static __device__ __forceinline__ void pack_one(const float* __restrict__ src,
                                                __half* __restrict__ dst,
                                                int OC, int IC, int KS,
                                                int oc_str, int ic_str, int k_str, int i) {
    int grp = KS / 4;
    int j = i % grp;
    int oc = (i / grp) % OC;
    int g = (i / (grp * OC)) & 3;
    int chunk = i / (grp * OC * 4);
    int CPK = IC / KS;
    int cc = chunk % CPK;
    int khw = chunk / CPK;
    int ic = cc * KS + g * grp + j;
    dst[i] = __float2half(src[(long)oc * oc_str + (long)ic * ic_str + khw * k_str]);
}

// Whh pack with class-interleaved row permutation: packed row prow = t*16 + cls*4 + du
// maps to original row cls*128 + t*4 + du. A 16-row MFMA tile then holds
// 4 classes x 4 units, so one wave (2 tiles) covers 8 units x all 4 classes.
static __device__ __forceinline__ void pack_whh_one(const float* __restrict__ src,
                                                    __half* __restrict__ dst, int i) {
    int j = i & 7;
    int prow = (i >> 3) & 511;
    int cg = i >> 12;            // chunk*4 + g
    int g = cg & 3, chunk = cg >> 2;
    int t = prow >> 4, rr = prow & 15;
    int cls = rr >> 2, du = rr & 3;
    int orig = cls * 128 + t * 4 + du;
    int ic = chunk * 32 + g * 8 + j;
    dst[i] = __float2half(src[orig * 128 + ic]);
}

// ---- fused weight prep ------------------------------------------------------------
__global__ __launch_bounds__(256) void prep_k(
        const float* __restrict__ w0, const float* __restrict__ w1,
        const float* __restrict__ w2, const float* __restrict__ w3,
        const float* __restrict__ Wihf, const float* __restrict__ Wihb,
        const float* __restrict__ Whhf, const float* __restrict__ Whhb,
        float* __restrict__ w0t, __half* __restrict__ w1p,
        __half* __restrict__ w2p, __half* __restrict__ w3p,
        __half* __restrict__ wfp, __half* __restrict__ wbp,
        __half* __restrict__ whhfp, __half* __restrict__ whhbp) {
    int i = blockIdx.x * 256 + threadIdx.x;
    if (i < 144) { int oc = i / 9, rem = i % 9; w0t[rem * 16 + oc] = w0[i]; return; }
    i -= 144;
    if (i < 4608) { pack_one(w1, w1p, 32, 16, 16, 144, 9, 1, i); return; }
    i -= 4608;
    if (i < 18432) { pack_one(w2, w2p, 64, 32, 32, 288, 9, 1, i); return; }
    i -= 18432;
    if (i < 73728) { pack_one(w3, w3p, 128, 64, 32, 576, 9, 1, i); return; }
    i -= 73728;
    if (i < 65536) { pack_one(Wihf, wfp, 512, 128, 32, 128, 1, 0, i); return; }
    i -= 65536;
    if (i < 65536) { pack_one(Wihb, wbp, 512, 128, 32, 128, 1, 0, i); return; }
    i -= 65536;
    if (i < 65536) { pack_whh_one(Whhf, whhfp, i); return; }
    i -= 65536;
    if (i < 65536) { pack_whh_one(Whhb, whhbp, i); return; }
}

__global__ void pack_wf16(const float* __restrict__ src, __half* __restrict__ dst,
                          int OC, int IC, int KS,
                          int oc_str, int ic_str, int k_str, int total) {
    int i = blockIdx.x * 256 + threadIdx.x;
    if (i >= total) return;
    pack_one(src, dst, OC, IC, KS, oc_str, ic_str, k_str, i);
}

// ---- conv0: 1->16 ch, VALU, NHWC f16 out (uint4-packed stores) --------------------
__global__ __launch_bounds__(256) void conv0_k(const float* __restrict__ in,
                                               const float* __restrict__ wT,
                                               const float* __restrict__ bias,
                                               __half* __restrict__ out) {
    __shared__ float wsm[9][16];
    __shared__ float bs[16];
    int tid = threadIdx.x;
    if (tid < 144) wsm[tid / 16][tid % 16] = wT[tid];
    if (tid < 16) bs[tid] = bias[tid];
    __syncthreads();
    int gid = blockIdx.x * 256 + tid;
    int ow = gid % 27;
    int t = (gid / 27) % 256;
    int bf = gid / (27 * 256);
    float acc[16];
#pragma unroll
    for (int o = 0; o < 16; o++) acc[o] = bs[o];
    int iw0 = ow * 3 - 1;
#pragma unroll
    for (int kh = 0; kh < 3; kh++) {
        int tt = t + kh - 1;
        if ((unsigned)tt >= 256u) continue;
        const float* ip = in + ((long)bf * 256 + tt) * 81;
#pragma unroll
        for (int kw = 0; kw < 3; kw++) {
            int iw = iw0 + kw;
            if ((unsigned)iw >= 81u) continue;
            float x = ip[iw];
#pragma unroll
            for (int o = 0; o < 16; o++) acc[o] += x * wsm[kh * 3 + kw][o];
        }
    }
    union OU { uint4 u; __half2 h2[4]; } o0, o1;
#pragma unroll
    for (int o = 0; o < 4; o++)
        o0.h2[o] = __floats2half2_rn(fmaxf(acc[2 * o], 0.f), fmaxf(acc[2 * o + 1], 0.f));
#pragma unroll
    for (int o = 0; o < 4; o++)
        o1.h2[o] = __floats2half2_rn(fmaxf(acc[8 + 2 * o], 0.f), fmaxf(acc[9 + 2 * o], 0.f));
    uint4* op = (uint4*)(out + (long)gid * 16);
    op[0] = o0.u;
    op[1] = o1.u;
}

// ---- MFMA implicit-GEMM conv: NHWC f16 in/out -------------------------------------
template<int IC, int OC, int WIN, int WOUT, int KS>
__global__ __launch_bounds__(256) void convM_k(const __half* __restrict__ in,
                                               const __half* __restrict__ wp,
                                               const float* __restrict__ bias,
                                               __half* __restrict__ out) {
    constexpr int NT = OC / 16;
    constexpr int CPK = IC / KS;
    constexpr int NCHUNK = 9 * CPK;
    constexpr int GRP = KS / 4;
    int tid = threadIdx.x;
    int lane = tid & 63;
    int wv = tid >> 6;
    int l15 = lane & 15;
    int g = lane >> 4;
    int m = blockIdx.x * 64 + wv * 16 + l15;
    int ow = m % WOUT;
    int t = (m / WOUT) % 256;
    int bf = m / (WOUT * 256);

    f4_t acc[NT];
#pragma unroll
    for (int nt = 0; nt < NT; nt++)
#pragma unroll
        for (int r = 0; r < 4; r++) acc[nt][r] = 0.f;

#pragma unroll
    for (int chunk = 0; chunk < NCHUNK; chunk++) {
        int khw = chunk / CPK, cc = chunk % CPK;
        int kh = khw / 3;
        int kw = khw - kh * 3;
        int tt = t + kh - 1;
        int iw = ow * 3 + kw - 1;
        bool ok = ((unsigned)tt < 256u) && ((unsigned)iw < (unsigned)WIN);
        long aoff = ok ? (((long)(bf * 256 + tt) * WIN + iw) * IC + cc * KS + g * GRP) : 0;
        if constexpr (KS == 32) {
            H8 af;
            af.u = *(const uint4*)(in + aoff);
            if (!ok) af.u = make_uint4(0u, 0u, 0u, 0u);
#pragma unroll
            for (int nt = 0; nt < NT; nt++) {
                H8 bf8;
                bf8.u = *(const uint4*)(wp + ((long)(chunk * 4 + g) * OC + nt * 16 + l15) * GRP);
                acc[nt] = __builtin_amdgcn_mfma_f32_16x16x32_f16(af.v, bf8.v, acc[nt], 0, 0, 0);
            }
        } else {
            H4 af;
            af.u = *(const uint2*)(in + aoff);
            if (!ok) af.u = make_uint2(0u, 0u);
#pragma unroll
            for (int nt = 0; nt < NT; nt++) {
                H4 bf4;
                bf4.u = *(const uint2*)(wp + ((long)(chunk * 4 + g) * OC + nt * 16 + l15) * GRP);
                acc[nt] = __builtin_amdgcn_mfma_f32_16x16x16f16(af.v, bf4.v, acc[nt], 0, 0, 0);
            }
        }
    }
    int orow = blockIdx.x * 64 + wv * 16 + g * 4;
#pragma unroll
    for (int nt = 0; nt < NT; nt++) {
        int oc = nt * 16 + l15;
        float b = bias[oc];
#pragma unroll
        for (int r = 0; r < 4; r++) {
            float v = fmaxf(acc[nt][r] + b, 0.f);
            out[(long)(orow + r) * OC + oc] = __float2half(v);
        }
    }
}

// ---- gates MFMA GEMM, TRANSPOSED output G'[(b*512+gate)*256 + tidx] ---------------
// fwd: tidx = t ; bwd: tidx = 255 - t (so lstm always reads ascending tidx).
// Output tile (128 t x 128 cols) is staged in LDS (reversal folded into the stage)
// and written back COALESCED: 256B contiguous per gate-row, 16 lanes x 16B.
// The old direct store scattered 8B per lane at 512B stride (~16x request rate).
__global__ __launch_bounds__(256) void gates_k(const __half* __restrict__ X,
                                               const __half* __restrict__ wpf,
                                               const __half* __restrict__ wpb,
                                               const float* __restrict__ bf1,
                                               const float* __restrict__ bf2,
                                               const float* __restrict__ bb1,
                                               const float* __restrict__ bb2,
                                               __half* __restrict__ Gf,
                                               __half* __restrict__ Gb) {
    int dir = blockIdx.z;
    const __half* wp = dir ? wpb : wpf;
    const float* b1 = dir ? bb1 : bf1;
    const float* b2 = dir ? bb2 : bf2;
    __half* G = dir ? Gb : Gf;
    int tid = threadIdx.x;
    int lane = tid & 63;
    int wv = tid >> 6;
    int l15 = lane & 15;
    int g = lane >> 4;
    int bx = blockIdx.x;
    int b = bx >> 1;                 // seq
    int t0 = (bx & 1) * 128;         // t-half of this block
    long r0 = (long)bx * 128 + wv * 32;
    int n0 = blockIdx.y * 128;

    __shared__ __align__(16) __half sh2[128][136];  // [col][t], +8 pad vs bank aliasing

    f4_t acc[2][8];
#pragma unroll
    for (int s = 0; s < 2; s++)
#pragma unroll
        for (int nt = 0; nt < 8; nt++)
#pragma unroll
            for (int r = 0; r < 4; r++) acc[s][nt][r] = 0.f;

#pragma unroll
    for (int chunk = 0; chunk < 4; chunk++) {
        H8 a0, a1;
        a0.u = *(const uint4*)(X + (r0 + l15) * 128 + chunk * 32 + g * 8);
        a1.u = *(const uint4*)(X + (r0 + 16 + l15) * 128 + chunk * 32 + g * 8);
#pragma unroll
        for (int nt = 0; nt < 8; nt++) {
            H8 bw;
            bw.u = *(const uint4*)(wp + ((long)(chunk * 4 + g) * 512 + n0 + nt * 16 + l15) * 8);
            acc[0][nt] = __builtin_amdgcn_mfma_f32_16x16x32_f16(a0.v, bw.v, acc[0][nt], 0, 0, 0);
            acc[1][nt] = __builtin_amdgcn_mfma_f32_16x16x32_f16(a1.v, bw.v, acc[1][nt], 0, 0, 0);
        }
    }

    // stage: sh2[col_local][t_local] (bwd: t reversed within the 128-tile)
    int tbw = wv * 32 + g * 4;
#pragma unroll
    for (int nt = 0; nt < 8; nt++) {
        int coll = nt * 16 + l15;
        int col = n0 + coll;
        float bias = b1[col] + b2[col];
#pragma unroll
        for (int s = 0; s < 2; s++) {
            int tbl = tbw + s * 16;
            U2H4 pk;
            if (!dir) {
#pragma unroll
                for (int r = 0; r < 4; r++) pk.h[r] = __float2half(acc[s][nt][r] + bias);
                *(uint2*)&sh2[coll][tbl] = pk.u;
            } else {
#pragma unroll
                for (int r = 0; r < 4; r++) pk.h[3 - r] = __float2half(acc[s][nt][r] + bias);
                *(uint2*)&sh2[coll][124 - tbl] = pk.u;
            }
        }
    }
    __syncthreads();

    // coalesced write-out: per gate-row 256B contiguous (16 lanes x 16B)
    int ts_start = dir ? 128 - t0 : t0;
#pragma unroll
    for (int cc = 0; cc < 8; cc++) {
        int idx = cc * 256 + tid;
        int coll = idx >> 4;
        int ch = idx & 15;
        uint4 v = *(const uint4*)&sh2[coll][ch * 8];
        *(uint4*)(G + ((long)(b * 512 + n0 + coll)) * 256 + ts_start + ch * 8) = v;
    }
}

// ---- LSTM recurrence: 256 blocks x 1024 thr (16 waves), 1 gate value per lane -----
// (unchanged from R5 — parked at ~184us; per-step serial skeleton is the floor)
__global__ __launch_bounds__(1024, 4) void lstm_k(const __half* __restrict__ Gf,
                                                  const __half* __restrict__ Gb,
                                                  const __half* __restrict__ whhfp,
                                                  const __half* __restrict__ whhbp,
                                                  __half* __restrict__ flat) {
    int bid = blockIdx.x;
    int dir = bid >> 7;
    int b0 = (bid & 127) * 2;
    const __half* G = dir ? Gb : Gf;
    const __half* wp = dir ? whhbp : whhfp;
    int tid = threadIdx.x;
    int w = tid >> 6;            // wave 0..15
    int lane = tid & 63;
    int l15 = lane & 15;
    int g2 = lane >> 4;          // class: 0=i, 1=f, 2=g, 3=o
    int chn = l15 >> 3;          // seq within block
    int u8 = l15 & 7;            // unit within wave's 8
    int unit = w * 8 + u8;       // 0..127
    int tsel = (u8 >> 2) & 1;
    int du = u8 & 3;

    // A-frags: 2 tiles x 4 k-chunks = 32 VGPRs/lane
    H8 afr[2][4];
#pragma unroll
    for (int t = 0; t < 2; t++) {
        int prow = (w * 2 + t) * 16 + l15;
#pragma unroll
        for (int c = 0; c < 4; c++)
            afr[t][c].u = *(const uint4*)(wp + ((long)((c * 4 + g2) * 512 + prow)) * 8);
    }

    __shared__ __align__(16) __half hbuf[2][2][128];
    if (tid < 256) hbuf[0][tid >> 7][tid & 127] = __float2half(0.f);
    __syncthreads();

    // this lane's single gate row in transposed G
    const __half* gb0 = G + (((long)(b0 + chn) * 512) + g2 * 128 + unit) * 256;

    float cst = 0.f;                         // cell state, valid on g2==1 lanes
    float ma = (g2 == 2) ? 2.f : 1.f;        // tanh(z) = 2*sigmoid(2z)-1 on g-lanes
    float mb = ma;
    float cb = (g2 == 2) ? -1.f : 0.f;
    const f4_t zero4 = {0.f, 0.f, 0.f, 0.f};

    H8 gc, gn;
    gc.u = *(const uint4*)(gb0);
    long fbase = (long)(b0 + chn) * 65536 + dir * 128 + unit;

    for (int to = 0; to < 32; to++) {
        if (to < 31) gn.u = *(const uint4*)(gb0 + (to + 1) * 8);
#pragma unroll
        for (int ti = 0; ti < 8; ti++) {
            int s = to * 8 + ti;
            int p = s & 1;
            H8 bfr[4];
#pragma unroll
            for (int c = 0; c < 4; c++)
                bfr[c].u = *(const uint4*)(&hbuf[p][chn][c * 32 + g2 * 8]);

            f4_t acc[2];
#pragma unroll
            for (int t = 0; t < 2; t++)
                acc[t] = __builtin_amdgcn_mfma_f32_16x16x32_f16(afr[t][0].v, bfr[0].v,
                                                                zero4, 0, 0, 0);
#pragma unroll
            for (int c = 1; c < 4; c++)
#pragma unroll
                for (int t = 0; t < 2; t++)
                    acc[t] = __builtin_amdgcn_mfma_f32_16x16x32_f16(afr[t][c].v, bfr[c].v,
                                                                    acc[t], 0, 0, 0);
            // select acc[tsel][du]
            f4_t at;
#pragma unroll
            for (int e = 0; e < 4; e++) at[e] = tsel ? acc[1][e] : acc[0][e];
            float lo = (du & 1) ? at[1] : at[0];
            float hi = (du & 1) ? at[3] : at[2];
            float ev = (du & 2) ? hi : lo;

            float z = ev + (float)gc.v[ti];
            float a = sigmoidf_(ma * z) * mb + cb;   // i,f,o: sigmoid; g: tanh

            float x1 = xswap32(a, lane);             // i<->g, f<->o (VALU permlane)
            float pi = a * x1;                       // on g2=0: sig(i)*tanh(g)
            float x2 = __shfl_xor(pi, 16, 64);       // g2=1 <- g2=0
            float cn = a * cst + x2;                 // on g2=1: sig(f)*c + pi
            cst = cn;
            float tc = tanhf_(cn);
            float x3 = xswap32(tc, lane);            // g2=3 <- g2=1 (VALU permlane)
            float h = a * x3;                        // on g2=3: sig(o)*tanh(c')

            if (g2 == 3) {
                __half hh = __float2half(h);
                int ts = dir ? (255 - s) : s;
                hbuf[p ^ 1][chn][unit] = hh;
                flat[fbase + (long)ts * 256] = hh;
            }
            wg_barrier_lds();
        }
        gc = gn;
    }
}

// ---- FC1 MFMA split-K: z[256][128] += flat16 @ fc1_w16^T --------------------------
__global__ __launch_bounds__(256) void fc1m_k(const __half* __restrict__ flat,
                                              const __half* __restrict__ wp,
                                              float* __restrict__ z) {
    int tid = threadIdx.x;
    int lane = tid & 63;
    int wv = tid >> 6;
    int l15 = lane & 15;
    int g = lane >> 4;
    int m0 = blockIdx.x * 64 + wv * 16;
    long k0 = (long)blockIdx.y * 1024;

    f4_t acc[8];
#pragma unroll
    for (int nt = 0; nt < 8; nt++)
#pragma unroll
        for (int r = 0; r < 4; r++) acc[nt][r] = 0.f;

    for (int c = 0; c < 32; c++) {
        long chunk = (k0 >> 5) + c;
        H8 af;
        af.u = *(const uint4*)(flat + (long)(m0 + l15) * 65536 + k0 + c * 32 + g * 8);
#pragma unroll
        for (int nt = 0; nt < 8; nt++) {
            H8 bw;
            bw.u = *(const uint4*)(wp + ((chunk * 4 + g) * 128 + nt * 16 + l15) * 8);
            acc[nt] = __builtin_amdgcn_mfma_f32_16x16x32_f16(af.v, bw.v, acc[nt], 0, 0, 0);
        }
    }
#pragma unroll
    for (int nt = 0; nt < 8; nt++)
#pragma unroll
        for (int r = 0; r < 4; r++)
            atomicAdd(&z[(m0 + g * 4 + r) * 128 + nt * 16 + l15], acc[nt][r]);
}

__global__ void zero_k(float* __restrict__ p, int n) {
    int i = blockIdx.x * 256 + threadIdx.x;
    if (i < n) p[i] = 0.f;
}

// ---- head -------------------------------------------------------------------------
__global__ __launch_bounds__(256) void head_k(const float* __restrict__ z,
                                              const float* __restrict__ b1,
                                              const float* __restrict__ fsw,
                                              const float* __restrict__ fsb,
                                              float* __restrict__ out) {
    __shared__ float sf[256];
    int r = threadIdx.x;
    float acc = fsb[0];
#pragma unroll
    for (int j4 = 0; j4 < 32; j4++) {
        float4 zv = *(const float4*)&z[r * 128 + j4 * 4];
        float4 bv = *(const float4*)&b1[j4 * 4];
        float4 wv = *(const float4*)&fsw[j4 * 4];
        acc += fmaxf(zv.x + bv.x, 0.f) * wv.x;
        acc += fmaxf(zv.y + bv.y, 0.f) * wv.y;
        acc += fmaxf(zv.z + bv.z, 0.f) * wv.z;
        acc += fmaxf(zv.w + bv.w, 0.f) * wv.w;
    }
    float val = sigmoidf_(acc) * 4.f + 1.f;
    out[16 + r] = val;
    sf[r] = val;
    __syncthreads();
    if (r < 16) {
        float m = 0.f;
#pragma unroll
        for (int f = 0; f < 16; f++) m += sf[r * 16 + f];
        out[r] = m * (1.f / 16.f);
    }
}

extern "C" void kernel_launch(void* const* d_in, const int* in_sizes, int n_in,
                              void* d_out, int out_size, void* d_ws, size_t ws_size,
                              hipStream_t stream) {
    const float* audio = (const float*)d_in[0];
    const float* w0 = (const float*)d_in[2];
    const float* b0 = (const float*)d_in[3];
    const float* w1 = (const float*)d_in[4];
    const float* b1 = (const float*)d_in[5];
    const float* w2 = (const float*)d_in[6];
    const float* b2 = (const float*)d_in[7];
    const float* w3 = (const float*)d_in[8];
    const float* b3 = (const float*)d_in[9];
    const float* Wih_f = (const float*)d_in[10];
    const float* Whh_f = (const float*)d_in[11];
    const float* bih_f = (const float*)d_in[12];
    const float* bhh_f = (const float*)d_in[13];
    const float* Wih_b = (const float*)d_in[14];
    const float* Whh_b = (const float*)d_in[15];
    const float* bih_b = (const float*)d_in[16];
    const float* bhh_b = (const float*)d_in[17];
    const float* fc1_w = (const float*)d_in[18];
    const float* fc1_b = (const float*)d_in[19];
    const float* fs_w = (const float*)d_in[20];
    const float* fs_b = (const float*)d_in[21];
    float* out = (float*)d_out;

    char* ws = (char*)d_ws;
    // lifetimes: out1 dies before Gf; out0 dies before flat16; Gf/Gb die before fc1p
    __half* Gf    = (__half*)(ws);                    // 67.1 MB (transposed layout)
    __half* out1  = (__half*)(ws);                    // 37.7 MB (pre-Gf)
    __half* fc1p  = (__half*)(ws);                    // 16.8 MB (post-lstm, in Gf)
    __half* Gb    = (__half*)(ws + 67108864);         // 67.1 MB
    __half* flat16= (__half*)(ws + 134217728);        // 33.6 MB
    __half* out0  = (__half*)(ws + 134217728);        // 56.6 MB (pre-flat16)
    __half* X     = (__half*)(ws + 201326592);        // 16.8 MB
    __half* out2  = (__half*)(ws + 218103808);        // 25.2 MB
    char* rd = ws + 243269632;
    float*  w0t   = (float*)(rd);
    __half* w1p   = (__half*)(rd + 1024);
    __half* w2p   = (__half*)(rd + 10240);
    __half* w3p   = (__half*)(rd + 47104);
    __half* wfp   = (__half*)(rd + 194560);
    __half* wbp   = (__half*)(rd + 325632);
    __half* whhfp = (__half*)(rd + 456704);
    __half* whhbp = (__half*)(rd + 587776);
    float*  zbuf  = (float*)(rd + 718848);

    // fused weight prep (1 launch)
    prep_k<<<1403, 256, 0, stream>>>(w0, w1, w2, w3, Wih_f, Wih_b, Whh_f, Whh_b,
                                     w0t, w1p, w2p, w3p, wfp, wbp, whhfp, whhbp);

    // conv chain (NHWC f16)
    conv0_k<<<6912, 256, 0, stream>>>(audio, w0t, b0, out0);
    convM_k<16, 32, 27, 9, 16><<<9216, 256, 0, stream>>>(out0, w1p, b1, out1);
    convM_k<32, 64, 9, 3, 32><<<3072, 256, 0, stream>>>(out1, w2p, b2, out2);
    convM_k<64, 128, 3, 1, 32><<<1024, 256, 0, stream>>>(out2, w3p, b3, X);

    // gates, both directions, transposed G output (LDS-transposed, coalesced stores)
    gates_k<<<dim3(512, 4, 2), 256, 0, stream>>>(X, wfp, wbp, bih_f, bhh_f,
                                                 bih_b, bhh_b, Gf, Gb);

    // recurrence (16 waves, 1 gate value/lane, permlane stitches, 1 lgkm barrier/step)
    lstm_k<<<256, 1024, 0, stream>>>(Gf, Gb, whhfp, whhbp, flat16);

    // FC head: pack fc1_w (into dead Gf region), split-K MFMA, head
    pack_wf16<<<32768, 256, 0, stream>>>(fc1_w, fc1p, 128, 65536, 32, 65536, 1, 0, 8388608);
    zero_k<<<128, 256, 0, stream>>>(zbuf, 256 * 128);
    fc1m_k<<<dim3(4, 64), 256, 0, stream>>>(flat16, fc1p, zbuf);
    head_k<<<1, 256, 0, stream>>>(zbuf, fc1_b, fs_w, fs_b, out);
}